// Round 20
// baseline (152.358 us; speedup 1.0000x reference)
//
#include <hip/hip_runtime.h>
#include <math.h>

#define L_SEQ 4096
#define D_HEAD 64
#define M_WIN 128
#define WIN 257              // 2*M+1
#define QB 8                 // q rows per tile
#define NT 2                 // tiles per block
#define QBLK 16              // q rows per block
#define KROWS 272            // staged K rows (covers both tiles' windows)
#define W 264                // per-tile window union
#define WF4 66               // W/4
#define ATTS 272             // att row stride (bf16 elements); uint2 stride 68
#define SCALE 0.125f         // 1/sqrt(64)

// wave-uniform lane read via VALU (v_readlane -> SGPR), not LDS pipe
#define RL(v, i) __uint_as_float(__builtin_amdgcn_readlane(__float_as_uint(v), (i)))

static __device__ __forceinline__ unsigned bfr(float x) {      // f32->bf16 RNE
    unsigned u = __float_as_uint(x);
    return (u + 0x7fffu + ((u >> 16) & 1u)) >> 16;
}
static __device__ __forceinline__ unsigned bfpack(float lo, float hi) {
    return bfr(lo) | (bfr(hi) << 16);
}
static __device__ __forceinline__ float bf2f(unsigned h) {     // bf16->f32
    return __uint_as_float(h << 16);
}

// K tile: [272 rows][8 uint4 slots], slot = c8 ^ (row&7); one uint4 = 8 bf16.
// att tile: [QB][272] bf16. Total LDS 39168 B -> 4 blocks/CU.
// Store schedule: per-tile D writes WINDOW ONLY (small; tile-1's V-load
// vmcnt wait only covers these); ALL zero stores issue at wave end with no
// subsequent loads -> they drain while replacement blocks compute (vmcnt
// coupling is per-wave; cross-wave drain is free).
__global__ __launch_bounds__(256, 4) void win_attn_kernel(
    const float* __restrict__ Q, const float* __restrict__ K,
    const float* __restrict__ V, float* __restrict__ OutO,
    float* __restrict__ OutA)
{
    extern __shared__ float smem[];
    uint4*  k_su  = (uint4*)smem;            // [272][8] uint4 = 34816 B
    unsigned short* att_h = (unsigned short*)(smem + 8704);   // [QB][ATTS] bf16

    const int t  = threadIdx.x;
    const int w  = t >> 6;                   // wave 0..3 -> rows {2w,2w+1}/tile
    const int ln = t & 63;
    const int bid = blockIdx.x;              // native mapping
    const int b      = bid >> 8;             // 256 blocks per batch
    const int q0_blk = (bid & 255) * QBLK;

    int s0_blk = q0_blk - M_WIN;
    if (s0_blk < 0) s0_blk = 0;
    if (s0_blk > L_SEQ - KROWS) s0_blk = L_SEQ - KROWS;   // <= 3824

    // ---------------- Phase A: stage 272-row K window (bf16, swizzled) ------
    {
        const float4* Kg = (const float4*)(K + ((size_t)(b * L_SEQ + s0_blk)) * D_HEAD);
        #pragma unroll 3
        for (int idx = t; idx < KROWS * 8; idx += 256) {
            int row = idx >> 3, c8 = idx & 7;               // rows all in-bounds
            float4 a  = Kg[(size_t)row * 16 + c8 * 2];
            float4 bb = Kg[(size_t)row * 16 + c8 * 2 + 1];
            uint4 d;
            d.x = bfpack(a.x, a.y);   d.y = bfpack(a.z, a.w);
            d.z = bfpack(bb.x, bb.y); d.w = bfpack(bb.z, bb.w);
            k_su[row * 8 + (c8 ^ (row & 7))] = d;
        }
    }
    // both tiles' q rows -> registers (before barrier; no stores in flight)
    float qv[NT][2];
    #pragma unroll
    for (int ti = 0; ti < NT; ++ti) {
        int rg = q0_blk + ti * QB + 2 * w;
        qv[ti][0] = Q[((size_t)(b * L_SEQ) + rg)     * D_HEAD + ln];
        qv[ti][1] = Q[((size_t)(b * L_SEQ) + rg + 1) * D_HEAD + ln];
    }
    // zero the att row pad (cols 264..271) for vectorized phase E reads
    if (ln < 16) {
        int r = 2 * w + (ln >> 3);
        att_h[r * ATTS + 264 + (ln & 7)] = 0;
    }
    __syncthreads();                         // the ONLY block-wide barrier

    // ---------------- NT tiles, wave-private after staging ------------------
    #pragma unroll
    for (int ti = 0; ti < NT; ++ti) {
        const int q0  = q0_blk + ti * QB;
        const int r0g = q0 + 2 * w;
        int s0 = q0 - M_WIN;
        if (s0 < 0) s0 = 0;
        if (s0 > L_SEQ - WIN) s0 = L_SEQ - WIN;
        const int off    = s0 - s0_blk;      // 0..15; off+wcount <= 272
        const int wcount = (L_SEQ - s0 < W) ? (L_SEQ - s0) : W;
        const float qv0 = qv[ti][0], qv1 = qv[ti][1];

        // ---------------- Phase B: scores; lane owns cols cg*64+ln ----------
        float p0[5], p1[5];
        {
            const uint4* kp[5];
            int msk[5];
            #pragma unroll
            for (int cg = 0; cg < 5; ++cg) {
                int colr = cg * 64 + ln;
                int col  = (colr < wcount) ? colr : wcount - 1;
                int row  = off + col;        // <= 271, in staged range
                kp[cg]  = k_su + (size_t)row * 8;
                msk[cg] = row & 7;
                p0[cg] = 0.f; p1[cg] = 0.f;
            }
            #pragma unroll
            for (int c8 = 0; c8 < 8; ++c8) {
                float a0 = RL(qv0, 8*c8+0), a1 = RL(qv0, 8*c8+1),
                      a2 = RL(qv0, 8*c8+2), a3 = RL(qv0, 8*c8+3),
                      a4 = RL(qv0, 8*c8+4), a5 = RL(qv0, 8*c8+5),
                      a6 = RL(qv0, 8*c8+6), a7 = RL(qv0, 8*c8+7);
                float b0 = RL(qv1, 8*c8+0), b1 = RL(qv1, 8*c8+1),
                      b2 = RL(qv1, 8*c8+2), b3 = RL(qv1, 8*c8+3),
                      b4 = RL(qv1, 8*c8+4), b5 = RL(qv1, 8*c8+5),
                      b6 = RL(qv1, 8*c8+6), b7 = RL(qv1, 8*c8+7);
                #pragma unroll
                for (int cg = 0; cg < 5; ++cg) {
                    uint4 kk = kp[cg][c8 ^ msk[cg]];
                    float e0 = __uint_as_float(kk.x << 16);
                    float e1 = __uint_as_float(kk.x & 0xffff0000u);
                    float e2 = __uint_as_float(kk.y << 16);
                    float e3 = __uint_as_float(kk.y & 0xffff0000u);
                    float e4 = __uint_as_float(kk.z << 16);
                    float e5 = __uint_as_float(kk.z & 0xffff0000u);
                    float e6 = __uint_as_float(kk.w << 16);
                    float e7 = __uint_as_float(kk.w & 0xffff0000u);
                    p0[cg] += a0*e0 + a1*e1 + a2*e2 + a3*e3
                            + a4*e4 + a5*e5 + a6*e6 + a7*e7;
                    p1[cg] += b0*e0 + b1*e1 + b2*e2 + b3*e3
                            + b4*e4 + b5*e5 + b6*e6 + b7*e7;
                }
            }
            #pragma unroll
            for (int cg = 0; cg < 5; ++cg) { p0[cg] *= SCALE; p1[cg] *= SCALE; }
        }

        // ---------------- Phase C: in-register masked softmax ---------------
        {
            int st0 = r0g - M_WIN;
            if (st0 < 0) st0 = 0;
            if (st0 > L_SEQ - WIN) st0 = L_SEQ - WIN;
            const int lo0 = st0 - s0;
            int st1 = r0g + 1 - M_WIN;
            if (st1 < 0) st1 = 0;
            if (st1 > L_SEQ - WIN) st1 = L_SEQ - WIN;
            const int lo1 = st1 - s0;

            float m0 = -1e30f, m1 = -1e30f;
            #pragma unroll
            for (int cg = 0; cg < 5; ++cg) {
                int colr = cg * 64 + ln;
                bool in0 = (colr >= lo0) && (colr < lo0 + WIN);
                bool in1 = (colr >= lo1) && (colr < lo1 + WIN);
                p0[cg] = in0 ? p0[cg] : -1e30f;
                p1[cg] = in1 ? p1[cg] : -1e30f;
                m0 = fmaxf(m0, p0[cg]);
                m1 = fmaxf(m1, p1[cg]);
            }
            #pragma unroll
            for (int o = 32; o >= 1; o >>= 1) {
                m0 = fmaxf(m0, __shfl_xor(m0, o));
                m1 = fmaxf(m1, __shfl_xor(m1, o));
            }
            float sum0 = 0.f, sum1 = 0.f;
            #pragma unroll
            for (int cg = 0; cg < 5; ++cg) {
                float e0 = (p0[cg] <= -1e29f) ? 0.f : __expf(p0[cg] - m0);
                float e1 = (p1[cg] <= -1e29f) ? 0.f : __expf(p1[cg] - m1);
                p0[cg] = e0; p1[cg] = e1;
                sum0 += e0; sum1 += e1;
            }
            #pragma unroll
            for (int o = 32; o >= 1; o >>= 1) {
                sum0 += __shfl_xor(sum0, o);
                sum1 += __shfl_xor(sum1, o);
            }
            const float inv0 = 1.f / sum0, inv1 = 1.f / sum1;
            #pragma unroll
            for (int cg = 0; cg < 5; ++cg) {
                int colr = cg * 64 + ln;
                if (colr < W) {
                    att_h[(2 * w)     * ATTS + colr] = (unsigned short)bfr(p0[cg] * inv0);
                    att_h[(2 * w + 1) * ATTS + colr] = (unsigned short)bfr(p1[cg] * inv1);
                }
            }
        }
        // No barrier: E/D read only this wave's own att rows (in-order LDS).

        // ---------------- Phase E: PV; b64 att reads ------------------------
        {
            const int cq = ln >> 4;
            const int dg = ln & 15;
            const float4* Vg4 = (const float4*)(V + ((size_t)(b * L_SEQ + s0)) * D_HEAD);
            const uint2* a2r0 = (const uint2*)(att_h + (2 * w) * ATTS);
            const uint2* a2r1 = (const uint2*)(att_h + (2 * w + 1) * ATTS);
            float4 acc0 = {0.f,0.f,0.f,0.f}, acc1 = {0.f,0.f,0.f,0.f};
            #pragma unroll 2
            for (int G = 0; G < 17; ++G) {   // 272 cols (pad p = 0)
                uint2 ua = a2r0[4 * G + cq];
                uint2 ub = a2r1[4 * G + cq];
                float pa[4], pb[4];
                pa[0] = bf2f(ua.x & 0xffffu); pa[1] = bf2f(ua.x >> 16);
                pa[2] = bf2f(ua.y & 0xffffu); pa[3] = bf2f(ua.y >> 16);
                pb[0] = bf2f(ub.x & 0xffffu); pb[1] = bf2f(ub.x >> 16);
                pb[2] = bf2f(ub.y & 0xffffu); pb[3] = bf2f(ub.y >> 16);
                #pragma unroll
                for (int e = 0; e < 4; ++e) {
                    int col  = 16 * G + 4 * cq + e;
                    int colc = (col < wcount) ? col : wcount - 1;  // p 0 there
                    float4 vv = Vg4[(size_t)colc * 16 + dg];
                    float fa = pa[e], fb = pb[e];
                    acc0.x += fa * vv.x; acc0.y += fa * vv.y;
                    acc0.z += fa * vv.z; acc0.w += fa * vv.w;
                    acc1.x += fb * vv.x; acc1.y += fb * vv.y;
                    acc1.z += fb * vv.z; acc1.w += fb * vv.w;
                }
            }
            #pragma unroll
            for (int o = 16; o <= 32; o <<= 1) {
                acc0.x += __shfl_xor(acc0.x, o); acc0.y += __shfl_xor(acc0.y, o);
                acc0.z += __shfl_xor(acc0.z, o); acc0.w += __shfl_xor(acc0.w, o);
                acc1.x += __shfl_xor(acc1.x, o); acc1.y += __shfl_xor(acc1.y, o);
                acc1.z += __shfl_xor(acc1.z, o); acc1.w += __shfl_xor(acc1.w, o);
            }
            if (ln < 16) {
                float4* o4 = (float4*)(OutO + ((size_t)(b * L_SEQ + r0g)) * D_HEAD);
                o4[dg]      = acc0;
                o4[16 + dg] = acc1;
            }
        }

        // ---------------- Phase D: WINDOW-ONLY stores for this tile ---------
        if ((s0 & 3) == 0) {
            const int zlo = s0 >> 2;
            #pragma unroll
            for (int r = 0; r < 2; ++r) {
                float4* rowp = (float4*)(OutA + ((size_t)(b * L_SEQ + r0g + r)) * L_SEQ);
                const uint2* arow = (const uint2*)(att_h + (2 * w + r) * ATTS);
                for (int i = ln; i < WF4; i += 64) {
                    uint2 uu = arow[i];
                    float4 wv;
                    wv.x = bf2f(uu.x & 0xffffu); wv.y = bf2f(uu.x >> 16);
                    wv.z = bf2f(uu.y & 0xffffu); wv.w = bf2f(uu.y >> 16);
                    rowp[zlo + i] = wv;      // 66 f4 per row
                }
            }
        } else {   // top-edge tiles (s0 = 3839): window f4 span [959, 1024)
            #pragma unroll
            for (int r = 0; r < 2; ++r) {
                float4* rowp = (float4*)(OutA + ((size_t)(b * L_SEQ + r0g + r)) * L_SEQ);
                const unsigned short* arow = att_h + (2 * w + r) * ATTS;
                for (int i = ln; i < 65; i += 64) {
                    int f4i = 959 + i;
                    int u   = 4 * f4i - s0;
                    float4 wv;
                    wv.x = (u     >= 0 && u     < W) ? bf2f(arow[u])     : 0.f;
                    wv.y = (u + 1 >= 0 && u + 1 < W) ? bf2f(arow[u + 1]) : 0.f;
                    wv.z = (u + 2 >= 0 && u + 2 < W) ? bf2f(arow[u + 2]) : 0.f;
                    wv.w = (u + 3 >= 0 && u + 3 < W) ? bf2f(arow[u + 3]) : 0.f;
                    rowp[f4i] = wv;
                }
            }
        }
    }

    // ---------------- Final phase: zero streaming (NO loads after this) -----
    __builtin_amdgcn_sched_barrier(0);       // keep zeros after all loads
    {
        const float4 z = {0.f, 0.f, 0.f, 0.f};
        #pragma unroll
        for (int ti = 0; ti < NT; ++ti) {
            const int q0  = q0_blk + ti * QB;
            const int r0g = q0 + 2 * w;
            int s0 = q0 - M_WIN;
            if (s0 < 0) s0 = 0;
            if (s0 > L_SEQ - WIN) s0 = L_SEQ - WIN;
            const bool al = ((s0 & 3) == 0);
            const int zloZ = al ? (s0 >> 2) : 959;        // window f4 start
            const int zhiZ = al ? ((s0 >> 2) + WF4) : 1024; // window f4 end
            #pragma unroll
            for (int r = 0; r < 2; ++r) {
                float4* rowp = (float4*)(OutA + ((size_t)(b * L_SEQ + r0g + r)) * L_SEQ);
                #pragma unroll 4
                for (int j = 0; j < 16; ++j) {
                    int f4i = j * 64 + ln;
                    if (f4i < zloZ || f4i >= zhiZ)
                        rowp[f4i] = z;       // fire-and-forget, drains cross-wave
                }
            }
        }
    }
}

extern "C" void kernel_launch(void* const* d_in, const int* in_sizes, int n_in,
                              void* d_out, int out_size, void* d_ws, size_t ws_size,
                              hipStream_t stream) {
    const float* Q = (const float*)d_in[0];
    const float* K = (const float*)d_in[1];
    const float* V = (const float*)d_in[2];
    float* OutO = (float*)d_out;
    float* OutA = OutO + (size_t)8 * L_SEQ * D_HEAD;

    const int smem_bytes = KROWS * 128 + QB * ATTS * 2;   // 39168 B -> 4 blk/CU
    hipFuncSetAttribute((const void*)win_attn_kernel,
                        hipFuncAttributeMaxDynamicSharedMemorySize, smem_bytes);

    dim3 grid(8 * (L_SEQ / QBLK));   // 2048 blocks = 2 clean generations
    dim3 block(256);
    win_attn_kernel<<<grid, block, smem_bytes, stream>>>(Q, K, V, OutO, OutA);
}